// Round 17
// baseline (53.010 us; speedup 1.0000x reference)
//
#include <hip/hip_runtime.h>
#include <math.h>

#define EMB 128
#define WIN 200
#define NT 64
#define BB 128
#define PSTRIDE 132   // per-(row,h) partial: 128 po + max + sum + mcount + pad

typedef short bf16x8 __attribute__((ext_vector_type(8)));
typedef float f32x4  __attribute__((ext_vector_type(4)));

__device__ __forceinline__ unsigned pk2bf16(float a, float b) {    // RNE pack
    unsigned ua = __float_as_uint(a), ub = __float_as_uint(b);
    ua = (ua + 0x7FFFu + ((ua >> 16) & 1u)) >> 16;
    ub = (ub + 0x7FFFu + ((ub >> 16) & 1u)) >> 16;
    return ua | (ub << 16);
}
__device__ __forceinline__ float bf_lo(unsigned u) { return __uint_as_float(u << 16); }
__device__ __forceinline__ float bf_hi(unsigned u) { return __uint_as_float(u & 0xFFFF0000u); }
__device__ __forceinline__ float rdlane(float v, int l) {
    return __uint_as_float(__builtin_amdgcn_readlane(__float_as_uint(v), l));
}

// ---------------------------------------------------------------------------
// proj via MFMA (R16-verified, unchanged). 128 rows/block, 512 thr.
// blocks [0,64) -> hp (titems); [64,264) -> hq (citems, +Wb); block 264 ->
// mask detect. fp32 row-major outputs.
// ---------------------------------------------------------------------------
__global__ __launch_bounds__(512, 4) void proj_kernel(
    const float* __restrict__ tvecs, const float* __restrict__ cvecs,
    const int* __restrict__ titems, const int* __restrict__ citems,
    const float* __restrict__ Ww, const float* __restrict__ Wbias,
    const int* __restrict__ mi, int* __restrict__ flag,
    float* __restrict__ hp_out, float* __restrict__ hq_out)
{
    __shared__ __align__(16) ushort s_A[128 * 128];   // 32 KB, swizzled
    __shared__ __align__(16) ushort s_B[128 * 128];   // 32 KB, swizzled
    __shared__ float s_bias[128];
    __shared__ int   sdet;

    const int tid = threadIdx.x;

    if (blockIdx.x == 264) {                          // mask-storage detect
        if (tid == 0) sdet = 0;
        __syncthreads();
        int bad = 0;
        for (int i = tid; i < 6400; i += 512)
            if ((unsigned)mi[i] > 1u) bad = 1;
        if (bad) sdet = 1;
        __syncthreads();
        if (tid == 0) flag[0] = sdet;
        return;
    }

    const bool is_hp = blockIdx.x < 64;
    const float* table = is_hp ? tvecs : cvecs;
    const int*   idx   = is_hp ? titems : citems;
    const int  rbase = (is_hp ? blockIdx.x : (blockIdx.x - 64)) * 128;
    const int  eoff  = is_hp ? 0 : EMB;

    if (tid < 128) s_bias[tid] = Wbias[tid];

    for (int i = tid; i < 4096; i += 512) {           // stage A (gather+cvt)
        int row = i >> 5, j = i & 31;
        float4 v = *(const float4*)&table[(size_t)idx[rbase + row] * 128 + 4 * j];
        uint2 p; p.x = pk2bf16(v.x, v.y); p.y = pk2bf16(v.z, v.w);
        *(uint2*)((char*)s_A + row * 256 + (((j >> 1) ^ (row & 7)) << 4) + (j & 1) * 8) = p;
    }
    for (int i = tid; i < 4096; i += 512) {           // stage B (Ww fp32 + cvt)
        int n = i >> 5, j = i & 31;
        float4 v = *(const float4*)&Ww[n * 256 + eoff + 4 * j];
        uint2 p; p.x = pk2bf16(v.x, v.y); p.y = pk2bf16(v.z, v.w);
        *(uint2*)((char*)s_B + n * 256 + (((j >> 1) ^ (n & 7)) << 4) + (j & 1) * 8) = p;
    }
    __syncthreads();

    const int wid = tid >> 6, l = tid & 63;
    const int rl = l & 15, kg = l >> 4;
    const int r0 = wid * 16;

    f32x4 acc[8];
#pragma unroll
    for (int i = 0; i < 8; ++i) acc[i] = (f32x4){0.f, 0.f, 0.f, 0.f};

    const int arow = r0 + rl;
#pragma unroll
    for (int s = 0; s < 4; ++s) {
        bf16x8 af = *(const bf16x8*)((const char*)s_A
                        + arow * 256 + ((((s << 2) + kg) ^ (arow & 7)) << 4));
#pragma unroll
        for (int nt = 0; nt < 8; ++nt) {
            int bn = nt * 16 + rl;
            bf16x8 bfr = *(const bf16x8*)((const char*)s_B
                            + bn * 256 + ((((s << 2) + kg) ^ (bn & 7)) << 4));
            acc[nt] = __builtin_amdgcn_mfma_f32_16x16x32_bf16(af, bfr, acc[nt], 0, 0, 0);
        }
    }

#pragma unroll
    for (int i = 0; i < 4; ++i) {
        size_t base = (size_t)(rbase + r0 + kg * 4 + i) * 128;
        if (is_hp) {
#pragma unroll
            for (int nt = 0; nt < 8; ++nt)
                hp_out[base + nt * 16 + rl] = acc[nt][i];
        } else {
#pragma unroll
            for (int nt = 0; nt < 8; ++nt) {
                int col = nt * 16 + rl;
                hq_out[base + col] = acc[nt][i] + s_bias[col];
            }
        }
    }
}

// ---------------------------------------------------------------------------
// attn_part: FLASH-STYLE W-SPLIT. Grid 512 = (b, t-half, w-half h). Each
// block scores its half of the COMPACTED window (cnt <= 64 when m <= 128)
// for 32 t's, computes local softmax (max,sum) + UNNORMALIZED po, writes
// partials. w-split adds blocks WITHOUT re-reading hq/k (R11's t-split
// amplified traffic 8x); LDS ~76 KB -> 2 blocks/CU co-resident (R16 was
// grid 256 = 1 block/CU, zero overlap, 39us measured).
// m>128 (never with random mask): h0 = full direct path, h1 = zero partial.
// ---------------------------------------------------------------------------
__global__ __launch_bounds__(512, 4) void attn_part(
    const float* __restrict__ cvecs, const int* __restrict__ citems,
    const void* __restrict__ mask_raw, const int* __restrict__ flagp,
    const float* __restrict__ hwg, const float* __restrict__ hp,
    const float* __restrict__ hq, float* __restrict__ part)
{
    __shared__ __align__(16) float4 s_hq4[32 * 64];   // [nc][w'] 32 KB
    __shared__ __align__(16) float4 s_k4[64 * 32];    // [w'][e4] 32 KB
    __shared__ __align__(16) ushort s_hp[32 * 128];   // [t][n] bf16 8 KB
    __shared__ float s_hw[128];
    __shared__ int s_ci[WIN];
    __shared__ int s_widx[WIN];
    __shared__ int s_m;

    const int tid  = threadIdx.x;
    const int bid  = blockIdx.x;
    const int b    = bid >> 2;
    const int tb   = ((bid >> 1) & 1) * 32;
    const int h    = bid & 1;
    const int lane = tid & 63;
    const int wid  = tid >> 6;
    const int t0   = wid * 4;

    // ---- stage hp (fp32 -> bf16), hw, citems; wave0 full compaction ----
    for (int i = tid; i < 1024; i += 512) {
        int t = i >> 5, e4 = i & 31;
        float4 v = *(const float4*)&hp[((size_t)(b * 64 + tb + t)) * 128 + e4 * 4];
        uint2 p; p.x = pk2bf16(v.x, v.y); p.y = pk2bf16(v.z, v.w);
        ((uint2*)s_hp)[i] = p;
    }
    if (tid < 128) s_hw[tid] = hwg[tid];
    if (tid < WIN) s_ci[tid] = citems[b * WIN + tid];
    if (wid == 0) {
        const int boolmode = flagp[0];
        const unsigned char* mb = (const unsigned char*)mask_raw;
        const int*           mi = (const int*)mask_raw;
        int base = 0;
#pragma unroll
        for (int r = 0; r < 4; ++r) {
            int w  = r * 64 + lane;
            int mv = 1;
            if (w < WIN) mv = boolmode ? (int)mb[b * WIN + w] : mi[b * WIN + w];
            unsigned long long act = __ballot(mv == 0);
            if (mv == 0)
                s_widx[base + __popcll(act & ((1ull << lane) - 1ull))] = w;
            base += __popcll(act);
        }
        if (lane == 0) s_m = base;
    }
    __syncthreads();

    const int m = s_m;
    const float4* hq4r = (const float4*)hq + (size_t)b * 200 * 32;  // [w][e4]
    const float4* hw4p = (const float4*)s_hw;

#define ZERO_OUT()                                                             \
    {                                                                          \
        _Pragma("unroll")                                                      \
        for (int j = 0; j < 4; ++j) {                                          \
            float* pb = part + ((size_t)((b * 64 + tb + t0 + j) * 2 + h)) * PSTRIDE; \
            *(float2*)(pb + lane * 2) = make_float2(0.f, 0.f);                 \
            if (lane == 0) { pb[128] = -1e30f; pb[129] = 0.f; pb[130] = 0.f; } \
        }                                                                      \
    }

#define SCB(J, HV)                                                             \
    va[J] += hwv.x * fmaxf(HV.x + pa, 0.f) + hwv.y * fmaxf(HV.y + pb_, 0.f)    \
           + hwv.z * fmaxf(HV.z + pc, 0.f) + hwv.w * fmaxf(HV.w + pd, 0.f);
#define SCB4(J, K, HV)                                                         \
    va[J][K] += hwv.x * fmaxf(HV.x + pa, 0.f) + hwv.y * fmaxf(HV.y + pb_, 0.f) \
              + hwv.z * fmaxf(HV.z + pc, 0.f) + hwv.w * fmaxf(HV.w + pd, 0.f);

    if (m <= 128) {
        const int mh0 = (m + 1) >> 1;                 // <= 64
        const int lo  = h ? mh0 : 0;
        const int cnt = h ? (m - mh0) : mh0;          // <= 64
        if (cnt == 0) { ZERO_OUT(); return; }

        // ---- stage compacted hq half + k half ----
        {
            const int w2 = tid & 63, nc0 = tid >> 6;  // 8 waves -> nc0 0..7
            if (w2 < cnt) {
                const int wi = s_widx[lo + w2];
#pragma unroll
                for (int nc = nc0; nc < 32; nc += 8)
                    s_hq4[nc * 64 + w2] = hq4r[(size_t)wi * 32 + nc];
            }
            const int e4 = tid & 31, w0 = tid >> 5;   // 16 row-groups
            const float4* cv4 = (const float4*)cvecs;
            for (int w2k = w0; w2k < cnt; w2k += 16)
                s_k4[w2k * 32 + e4] = cv4[(size_t)s_ci[s_widx[lo + w2k]] * 32 + e4];
        }
        __syncthreads();

        // ---- score (one 64-lane tile) ----
        float va[4];
        va[0] = va[1] = va[2] = va[3] = 0.f;
#pragma unroll 4
        for (int nc = 0; nc < 32; ++nc) {
            float4 hv  = s_hq4[nc * 64 + lane];
            float4 hwv = hw4p[nc];
#pragma unroll
            for (int jt = 0; jt < 4; ++jt) {
                uint2 pu = *(const uint2*)&s_hp[(t0 + jt) * 128 + nc * 4];
                float pa = bf_lo(pu.x), pb_ = bf_hi(pu.x), pc = bf_lo(pu.y), pd = bf_hi(pu.y);
                SCB(jt, hv)
            }
        }

        // ---- local softmax: keep e (unnormalized), mx, sum per t ----
        float mxs[4], sms[4];
#pragma unroll
        for (int j = 0; j < 4; ++j) {
            float v = (lane < cnt) ? va[j] : -1e30f;
            float mx = v;
#pragma unroll
            for (int off = 32; off; off >>= 1) mx = fmaxf(mx, __shfl_xor(mx, off));
            float e = (v <= -1e29f) ? 0.f : __expf(v - mx);
            float sum = e;
#pragma unroll
            for (int off = 32; off; off >>= 1) sum += __shfl_xor(sum, off);
            va[j] = e; mxs[j] = mx; sms[j] = sum;
        }

        // ---- partial PV (unnormalized) from LDS k ----
        float2 po[4];
#pragma unroll
        for (int j = 0; j < 4; ++j) po[j] = make_float2(0.f, 0.f);
        const float2* s_k2 = (const float2*)s_k4;
        for (int w = 0; w < cnt; ++w) {
            float2 kv = s_k2[w * 64 + lane];
            float a0 = rdlane(va[0], w);
            float a1 = rdlane(va[1], w);
            float a2 = rdlane(va[2], w);
            float a3 = rdlane(va[3], w);
            po[0].x += a0 * kv.x; po[0].y += a0 * kv.y;
            po[1].x += a1 * kv.x; po[1].y += a1 * kv.y;
            po[2].x += a2 * kv.x; po[2].y += a2 * kv.y;
            po[3].x += a3 * kv.x; po[3].y += a3 * kv.y;
        }

#pragma unroll
        for (int j = 0; j < 4; ++j) {
            float* pb = part + ((size_t)((b * 64 + tb + t0 + j) * 2 + h)) * PSTRIDE;
            *(float2*)(pb + lane * 2) = po[j];
            if (lane == 0) { pb[128] = mxs[j]; pb[129] = sms[j]; pb[130] = (float)cnt; }
        }
    } else {
        // ================= m > 128 (rare) =================
        if (h == 1) { ZERO_OUT(); return; }
        int wreg[4];
        const int mc = m - 1;
#pragma unroll
        for (int kt = 0; kt < 4; ++kt) wreg[kt] = s_widx[min(kt * 64 + lane, mc)];

        float va[4][4];
#pragma unroll
        for (int j = 0; j < 4; ++j)
#pragma unroll
            for (int k = 0; k < 4; ++k) va[j][k] = 0.f;

#pragma unroll 2
        for (int nc = 0; nc < 32; ++nc) {
            float4 hv0 = hq4r[(size_t)wreg[0] * 32 + nc];
            float4 hv1 = hq4r[(size_t)wreg[1] * 32 + nc];
            float4 hv2 = hq4r[(size_t)wreg[2] * 32 + nc];
            float4 hv3 = hq4r[(size_t)wreg[3] * 32 + nc];
            float4 hwv = hw4p[nc];
#pragma unroll
            for (int jt = 0; jt < 4; ++jt) {
                uint2 pu = *(const uint2*)&s_hp[(t0 + jt) * 128 + nc * 4];
                float pa = bf_lo(pu.x), pb_ = bf_hi(pu.x), pc = bf_lo(pu.y), pd = bf_hi(pu.y);
                SCB4(jt, 0, hv0) SCB4(jt, 1, hv1) SCB4(jt, 2, hv2) SCB4(jt, 3, hv3)
            }
        }

        float mxs[4], sms[4];
#pragma unroll
        for (int j = 0; j < 4; ++j) {
            float mx = -1e30f;
#pragma unroll
            for (int kt = 0; kt < 4; ++kt) {
                float v = (kt * 64 + lane < m) ? va[j][kt] : -1e30f;
                va[j][kt] = v;
                mx = fmaxf(mx, v);
            }
#pragma unroll
            for (int off = 32; off; off >>= 1) mx = fmaxf(mx, __shfl_xor(mx, off));
            float sum = 0.f;
#pragma unroll
            for (int kt = 0; kt < 4; ++kt) {
                float e = (va[j][kt] <= -1e29f) ? 0.f : __expf(va[j][kt] - mx);
                va[j][kt] = e;
                sum += e;
            }
#pragma unroll
            for (int off = 32; off; off >>= 1) sum += __shfl_xor(sum, off);
            mxs[j] = mx; sms[j] = sum;
        }

        float2 po[4];
#pragma unroll
        for (int j = 0; j < 4; ++j) po[j] = make_float2(0.f, 0.f);
        const char* cvb = (const char*)cvecs;
#pragma unroll
        for (int kt = 0; kt < 4; ++kt) {
            if (kt * 64 < m) {
                const int wn = min(64, m - kt * 64);
                for (int w = 0; w < wn; ++w) {
                    unsigned off = (unsigned)s_ci[s_widx[kt * 64 + w]] * 512u;
                    float2 kv = *(const float2*)(cvb + off + lane * 8);
                    float a0 = rdlane(va[0][kt], w);
                    float a1 = rdlane(va[1][kt], w);
                    float a2 = rdlane(va[2][kt], w);
                    float a3 = rdlane(va[3][kt], w);
                    po[0].x += a0 * kv.x; po[0].y += a0 * kv.y;
                    po[1].x += a1 * kv.x; po[1].y += a1 * kv.y;
                    po[2].x += a2 * kv.x; po[2].y += a2 * kv.y;
                    po[3].x += a3 * kv.x; po[3].y += a3 * kv.y;
                }
            }
        }
#pragma unroll
        for (int j = 0; j < 4; ++j) {
            float* pb = part + ((size_t)((b * 64 + tb + t0 + j) * 2 + h)) * PSTRIDE;
            *(float2*)(pb + lane * 2) = po[j];
            if (lane == 0) { pb[128] = mxs[j]; pb[129] = sms[j]; pb[130] = (float)m; }
        }
    }
#undef SCB
#undef SCB4
#undef ZERO_OUT
}

// ---------------------------------------------------------------------------
// combine: out[t] = (c0*po0 + c1*po1) * invn / (c0*s0 + c1*s1),
// c_h = e^{mx_h - M}, M = max(mx0, mx1), invn = 1/sqrt(800 + m0c + m1c).
// 4 waves/block, 1 t-row per wave. Grid 2048.
// ---------------------------------------------------------------------------
__global__ __launch_bounds__(256) void combine_kernel(
    const float* __restrict__ part, float* __restrict__ outp)
{
    const int lane = threadIdx.x & 63;
    const int wid  = threadIdx.x >> 6;
    const int row  = blockIdx.x * 4 + wid;            // 0..8191

    const float* p0 = part + (size_t)row * 2 * PSTRIDE;
    const float* p1 = p0 + PSTRIDE;
    float mx0 = p0[128], s0 = p0[129], c0m = p0[130];
    float mx1 = p1[128], s1 = p1[129], c1m = p1[130];
    float M  = fmaxf(mx0, mx1);
    float c0 = (s0 > 0.f) ? __expf(mx0 - M) : 0.f;
    float c1 = (s1 > 0.f) ? __expf(mx1 - M) : 0.f;
    float den = c0 * s0 + c1 * s1;
    float invn = 1.f / sqrtf(800.f + c0m + c1m);
    float scale = (den > 0.f) ? (invn / den) : 0.f;

    float2 a = *(const float2*)(p0 + lane * 2);
    float2 q = *(const float2*)(p1 + lane * 2);
    float2 r;
    r.x = (c0 * a.x + c1 * q.x) * scale;
    r.y = (c0 * a.y + c1 * q.y) * scale;
    *(float2*)&outp[(size_t)row * 128 + lane * 2] = r;
}

// ---------------------------------------------------------------------------
extern "C" void kernel_launch(void* const* d_in, const int* in_sizes, int n_in,
                              void* d_out, int out_size, void* d_ws, size_t ws_size,
                              hipStream_t stream) {
    const float* tvecs = (const float*)d_in[0];
    const float* cvecs = (const float*)d_in[1];
    const float* Ww    = (const float*)d_in[2];
    const float* Wb    = (const float*)d_in[3];
    const float* hw    = (const float*)d_in[4];
    // d_in[5] = h_b : unused (softmax shift-invariance)
    const int* titems  = (const int*)d_in[6];
    const int* citems  = (const int*)d_in[7];
    const void* mask   = d_in[8];
    float* out         = (float*)d_out;

    // ws: flag 256 B | hp (4 MB) | hq (13.1 MB) | partials (8192*2*132*4 = 8.65 MB)
    const size_t hp_elems   = (size_t)BB * NT * 128;
    const size_t hq_elems   = (size_t)BB * WIN * 128;
    const size_t part_elems = (size_t)BB * NT * 2 * PSTRIDE;
    const size_t needed = 256 + (hp_elems + hq_elems + part_elems) * 4;
    if (ws_size < needed) return;

    int*   flag    = (int*)d_ws;
    float* hp_ws   = (float*)((char*)d_ws + 256);
    float* hq_ws   = hp_ws + hp_elems;
    float* part_ws = hq_ws + hq_elems;

    proj_kernel<<<265, 512, 0, stream>>>(tvecs, cvecs, titems, citems,
                                         Ww, Wb, (const int*)mask, flag,
                                         hp_ws, hq_ws);
    attn_part<<<BB * 4, 512, 0, stream>>>(cvecs, citems, mask, flag,
                                          hw, hp_ws, hq_ws, part_ws);
    combine_kernel<<<2048, 256, 0, stream>>>(part_ws, out);
}